// Round 3
// baseline (234.486 us; speedup 1.0000x reference)
//
#include <hip/hip_runtime.h>
#include <hip/hip_bf16.h>

#define NN 50000
#define EE 600000
#define DD 128
#define LL 3
#define LN_EPS 1e-5f
#define CAP 64                      // bucket capacity; max in-degree ~30 for this graph
#define CNTS 16                     // ints per degree counter (64B line each: kills atomic line contention)
#define ALD 136                     // padded LDS row stride (shorts)
#define POOL 16                     // nodes per block tile (NN = 3125 * 16 exactly)
#define NTILES (NN / POOL)          // 3125
#define FILLB ((EE + 255) / 256)    // 2344 blocks, one edge per thread

typedef __attribute__((ext_vector_type(8))) short short8;
typedef __attribute__((ext_vector_type(4))) float floatx4;
typedef __attribute__((ext_vector_type(4))) unsigned uintx4;

__device__ inline unsigned short f2bf(float f) {
    union { float f; unsigned u; } a; a.f = f;
    unsigned r = a.u + 0x7fffu + ((a.u >> 16) & 1u);  // RNE (finite values)
    return (unsigned short)(r >> 16);
}

// 16B gather with guaranteed issue (inline asm): compiler at low VGPR budget
// serializes these to ~1 outstanding load; asm + explicit vmcnt forces MLP.
__device__ inline uintx4 gload4(const unsigned short* p) {
    uintx4 r;
    asm volatile("global_load_dwordx4 %0, %1, off" : "=v"(r) : "v"(p));
    return r;
}

// ------- init: zero cnt (in-kernel, NOT hipMemsetAsync: the runtime expands
// that into a 256 MiB fillBuffer costing 44 us/iter) + W -> Wt bf16 ---------

__global__ __launch_bounds__(256) void init_kernel(const float* __restrict__ W,
                                                   unsigned short* __restrict__ Wt,
                                                   int* __restrict__ cnt) {
    int tid = blockIdx.x * 256 + threadIdx.x;
    // zero NN*CNTS ints via int4 stores (800000 ints = 200000 int4s)
    for (int i = tid; i < NN * CNTS / 4; i += gridDim.x * 256)
        ((int4*)cnt)[i] = make_int4(0, 0, 0, 0);
    // Wt[l][n][k] = bf16(W[l][k][n])
    for (int i = tid; i < LL * DD * DD; i += gridDim.x * 256) {
        int l = i >> 14, n = (i >> 7) & 127, k = i & 127;
        Wt[i] = f2bf(W[(l << 14) + k * DD + n]);
    }
}

// ------ fill: one edge per thread, padded counters ---------------------------

__global__ __launch_bounds__(256) void fill_kernel(
    const int* __restrict__ src, const int* __restrict__ dst,
    int* __restrict__ cnt, int* __restrict__ csrc) {
    int e = blockIdx.x * 256 + threadIdx.x;
    if (e < EE) {
        int d = dst[e];
        int s = src[e];
        int pos = atomicAdd(&cnt[d * CNTS], 1);
        csrc[(size_t)d * CAP + pos] = s;
    }
}

// ------ gemm0: Tb' = bf16( (x @ W0) * dinv )  (pre-scaled rows) ------------
// 3125 blocks x 256 thr, 16-row tile. MFMA: 4 waves, 16x32 each. Epilogue
// scales row n by dinv[n] = rsqrt(deg+1) then transposes through LDS.

__global__ __launch_bounds__(256) void gemm0_kernel(
    const float* __restrict__ A, const unsigned short* __restrict__ Wt,
    const int* __restrict__ cnt, unsigned short* __restrict__ Cb) {
    __shared__ unsigned short alds[POOL * ALD];
    __shared__ float s_dinv[POOL];
    int tid = threadIdx.x;
    int lane = tid & 63;
    int w = tid >> 6;
    int nodebase = blockIdx.x * POOL;

    if (tid < POOL)
        s_dinv[tid] = rsqrtf((float)(cnt[(nodebase + tid) * CNTS] + 1));

    // stage 16 rows of x (f32 -> bf16) into LDS
    {
        int row = tid >> 4;
        int kc = (tid & 15) * 8;
        const float* ap = &A[(size_t)(nodebase + row) * DD + kc];
        float4 v0 = *(const float4*)&ap[0];
        float4 v1 = *(const float4*)&ap[4];
        float fv[8] = {v0.x, v0.y, v0.z, v0.w, v1.x, v1.y, v1.z, v1.w};
        unsigned short uv[8];
        #pragma unroll
        for (int q = 0; q < 8; q++) uv[q] = f2bf(fv[q]);
        *(uint4*)&alds[row * ALD + kc] = *(uint4*)&uv[0];
    }
    __syncthreads();

    // MFMA: 4 waves, 16x32 slice each
    int cbase = w * 32;
    int kq = (lane >> 4) * 8;
    int mrow = lane & 15;
    floatx4 acc[2] = {{0.f,0.f,0.f,0.f},{0.f,0.f,0.f,0.f}};
    #pragma unroll
    for (int t = 0; t < 4; t++) {
        short8 a = *(const short8*)&alds[mrow * ALD + t * 32 + kq];
        #pragma unroll
        for (int j = 0; j < 2; j++) {
            short8 b = *(const short8*)&Wt[(cbase + j * 16 + (lane & 15)) * DD + t * 32 + kq];
            acc[j] = __builtin_amdgcn_mfma_f32_16x16x32_bf16(a, b, acc[j], 0, 0, 0);
        }
    }
    __syncthreads();   // alds reads done before transpose overwrites

    // epilogue: scale by dinv[row], transpose through LDS, coalesced stores
    {
        int r0 = (lane >> 4) * 4;
        #pragma unroll
        for (int i = 0; i < 4; i++) {
            float dvr = s_dinv[r0 + i];
            #pragma unroll
            for (int j = 0; j < 2; j++)
                alds[(r0 + i) * ALD + cbase + j * 16 + (lane & 15)] = f2bf(acc[j][i] * dvr);
        }
    }
    __syncthreads();
    {
        int srow = tid >> 4;
        int scol = (tid & 15) * 8;
        *(uint4*)&Cb[(size_t)(nodebase + srow) * DD + scol] =
            *(uint4*)&alds[srow * ALD + scol];
    }
}

// --------- shared agg helper: Tb rows are PRE-SCALED by dinv[src] -----------
// agg = sum of neighbor rows + self row (all weight-free); caller applies
// the final *dinv[dst] inside the bias fmaf. 16-lane group, lane owns 8 feats.

__device__ inline void acc_row(float* acc, uintx4 t) {
    #pragma unroll
    for (int q = 0; q < 4; q++) {
        union { unsigned x; float f; } lo, hi;
        lo.x = t[q] << 16;
        hi.x = t[q] & 0xffff0000u;
        acc[2 * q]     += lo.f;
        acc[2 * q + 1] += hi.f;
    }
}

__device__ inline void agg_node(const unsigned short* __restrict__ Tb,
                                const int* __restrict__ cnt, const int* __restrict__ csrc,
                                const float* bv, const float* wv, const float* cv,
                                float alpha, int node, int f8, float* yv, float* dv_out) {
    int deg = cnt[node * CNTS];
    float dv = rsqrtf((float)(deg + 1));
    *dv_out = dv;
    const int* row = &csrc[(size_t)node * CAP];

    float acc[8] = {};
    acc_row(acc, *(const uintx4*)&Tb[((unsigned)node << 7) + f8]);  // self-loop (pre-scaled)

    int k = 0;
    for (; k + 4 <= deg; k += 4) {
        int4 ss = *(const int4*)&row[k];
        const unsigned short* p0 = &Tb[((unsigned)ss.x << 7) + f8];
        const unsigned short* p1 = &Tb[((unsigned)ss.y << 7) + f8];
        const unsigned short* p2 = &Tb[((unsigned)ss.z << 7) + f8];
        const unsigned short* p3 = &Tb[((unsigned)ss.w << 7) + f8];
        uintx4 t0 = gload4(p0);
        uintx4 t1 = gload4(p1);
        uintx4 t2 = gload4(p2);
        uintx4 t3 = gload4(p3);
        asm volatile("s_waitcnt vmcnt(0)" ::: "memory");
        __builtin_amdgcn_sched_barrier(0);          // rule #18: pin uses after the wait
        acc_row(acc, t0); acc_row(acc, t1);
        acc_row(acc, t2); acc_row(acc, t3);
    }
    for (; k < deg; k++) {
        int s = row[k];
        acc_row(acc, *(const uintx4*)&Tb[((unsigned)s << 7) + f8]);
    }

    float a[8];
    float s1 = 0.f, s2 = 0.f;
    #pragma unroll
    for (int q = 0; q < 8; q++) {
        a[q] = fmaf(acc[q], dv, bv[q]);
        s1 += a[q]; s2 += a[q] * a[q];
    }
    #pragma unroll
    for (int off = 8; off > 0; off >>= 1) {
        s1 += __shfl_xor(s1, off, 16);
        s2 += __shfl_xor(s2, off, 16);
    }
    float mu = s1 * (1.f / DD);
    float var = s2 * (1.f / DD) - mu * mu;
    float rstd = rsqrtf(var + LN_EPS);
    #pragma unroll
    for (int q = 0; q < 8; q++) {
        float y = (a[q] - mu) * rstd * wv[q] + cv[q];
        yv[q] = (y >= 0.f) ? y : alpha * y;
    }
}

// ------- fused agg(layer l) + gemm(layer l+1): Tb' -> Tout' (pre-scaled) ----

__global__ __launch_bounds__(256) void aggemm_kernel(
    const unsigned short* __restrict__ Tb, const int* __restrict__ cnt,
    const int* __restrict__ csrc,
    const float* __restrict__ bias, const float* __restrict__ lnw,
    const float* __restrict__ lnb, const float* __restrict__ alphas, int layer,
    const unsigned short* __restrict__ Wt, unsigned short* __restrict__ Tout) {
    __shared__ unsigned short alds[POOL * ALD];
    __shared__ float s_dinv[POOL];
    int tid = threadIdx.x;
    int g = tid >> 4;
    int lane16 = tid & 15;
    int f8 = lane16 * 8;
    int nodebase = blockIdx.x * POOL;

    float4 b0 = *(const float4*)&bias[f8];
    float4 b1 = *(const float4*)&bias[f8 + 4];
    float4 w0 = *(const float4*)&lnw[f8];
    float4 w1 = *(const float4*)&lnw[f8 + 4];
    float4 c0 = *(const float4*)&lnb[f8];
    float4 c1 = *(const float4*)&lnb[f8 + 4];
    float bv[8] = {b0.x, b0.y, b0.z, b0.w, b1.x, b1.y, b1.z, b1.w};
    float wv[8] = {w0.x, w0.y, w0.z, w0.w, w1.x, w1.y, w1.z, w1.w};
    float cv[8] = {c0.x, c0.y, c0.z, c0.w, c1.x, c1.y, c1.z, c1.w};
    float alpha = alphas[layer];

    {   // NN == 3125*16: node always in range
        int node = nodebase + g;
        float yv[8], dv;
        agg_node(Tb, cnt, csrc, bv, wv, cv, alpha, node, f8, yv, &dv);
        if (lane16 == 0) s_dinv[g] = dv;
        unsigned short pv[8];
        #pragma unroll
        for (int q = 0; q < 8; q++) pv[q] = f2bf(yv[q]);
        *(uint4*)&alds[g * ALD + f8] = *(uint4*)&pv[0];
    }
    __syncthreads();

    // MFMA: C = Y @ W_{l+1}, rows pre-scaled by dinv in the epilogue.
    int lane = tid & 63;
    int w = tid >> 6;
    int cbase = w * 32;
    int kq = (lane >> 4) * 8;
    int mrow = lane & 15;
    floatx4 acc[2] = {{0.f,0.f,0.f,0.f},{0.f,0.f,0.f,0.f}};
    #pragma unroll
    for (int t = 0; t < 4; t++) {
        short8 a = *(const short8*)&alds[mrow * ALD + t * 32 + kq];
        #pragma unroll
        for (int j = 0; j < 2; j++) {
            short8 b = *(const short8*)&Wt[(cbase + j * 16 + (lane & 15)) * DD + t * 32 + kq];
            acc[j] = __builtin_amdgcn_mfma_f32_16x16x32_bf16(a, b, acc[j], 0, 0, 0);
        }
    }
    __syncthreads();   // alds reads done before transpose overwrites

    {
        int r0 = (lane >> 4) * 4;
        #pragma unroll
        for (int i = 0; i < 4; i++) {
            float dvr = s_dinv[r0 + i];
            #pragma unroll
            for (int j = 0; j < 2; j++)
                alds[(r0 + i) * ALD + cbase + j * 16 + (lane & 15)] = f2bf(acc[j][i] * dvr);
        }
    }
    __syncthreads();
    {
        int srow = tid >> 4;
        int scol = (tid & 15) * 8;
        *(uint4*)&Tout[(size_t)(nodebase + srow) * DD + scol] =
            *(uint4*)&alds[srow * ALD + scol];
    }
}

// ---------------- final agg: layer 2, f32 output ----------------

__global__ __launch_bounds__(256) void agg_final_kernel(
    const unsigned short* __restrict__ Tb, const int* __restrict__ cnt,
    const int* __restrict__ csrc,
    const float* __restrict__ bias, const float* __restrict__ lnw,
    const float* __restrict__ lnb, const float* __restrict__ alphas, int layer,
    float* __restrict__ out) {
    int g = threadIdx.x >> 4;
    int lane16 = threadIdx.x & 15;
    int f8 = lane16 * 8;
    int node = blockIdx.x * POOL + g;

    float4 b0 = *(const float4*)&bias[f8];
    float4 b1 = *(const float4*)&bias[f8 + 4];
    float4 w0 = *(const float4*)&lnw[f8];
    float4 w1 = *(const float4*)&lnw[f8 + 4];
    float4 c0 = *(const float4*)&lnb[f8];
    float4 c1 = *(const float4*)&lnb[f8 + 4];
    float bv[8] = {b0.x, b0.y, b0.z, b0.w, b1.x, b1.y, b1.z, b1.w};
    float wv[8] = {w0.x, w0.y, w0.z, w0.w, w1.x, w1.y, w1.z, w1.w};
    float cv[8] = {c0.x, c0.y, c0.z, c0.w, c1.x, c1.y, c1.z, c1.w};

    float yv[8], dv;
    agg_node(Tb, cnt, csrc, bv, wv, cv, alphas[layer], node, f8, yv, &dv);

    float* op = &out[(size_t)node * DD + f8];
    *(float4*)&op[0] = make_float4(yv[0], yv[1], yv[2], yv[3]);
    *(float4*)&op[4] = make_float4(yv[4], yv[5], yv[6], yv[7]);
}

// ---------------- launch ----------------

extern "C" void kernel_launch(void* const* d_in, const int* in_sizes, int n_in,
                              void* d_out, int out_size, void* d_ws, size_t ws_size,
                              hipStream_t stream) {
    const float* x    = (const float*)d_in[0];
    const int*   ei   = (const int*)d_in[1];
    const float* Ws   = (const float*)d_in[2];
    const float* bs   = (const float*)d_in[3];
    const float* lnw  = (const float*)d_in[4];
    const float* lnb  = (const float*)d_in[5];
    const float* alphas = (const float*)d_in[6];
    float* out = (float*)d_out;

    const int* src = ei;
    const int* dst = ei + EE;

    char* ws = (char*)d_ws;
    size_t off = 0;
    auto alloc = [&](size_t bytes) -> void* {
        void* p = ws + off;
        off = (off + bytes + 255) & ~(size_t)255;
        return p;
    };
    int* cnt  = (int*)alloc((size_t)NN * CNTS * sizeof(int));
    int* csrc = (int*)alloc((size_t)NN * CAP * sizeof(int));
    unsigned short* wt    = (unsigned short*)alloc((size_t)LL * DD * DD * sizeof(unsigned short));
    unsigned short* tbufA = (unsigned short*)alloc((size_t)NN * DD * sizeof(unsigned short));
    unsigned short* tbufB = (unsigned short*)alloc((size_t)NN * DD * sizeof(unsigned short));

    init_kernel<<<512, 256, 0, stream>>>(Ws, wt, cnt);
    fill_kernel<<<FILLB, 256, 0, stream>>>(src, dst, cnt, csrc);
    gemm0_kernel<<<NTILES, 256, 0, stream>>>(x, wt, cnt, tbufA);

    aggemm_kernel<<<NTILES, 256, 0, stream>>>(tbufA, cnt, csrc,
                                              bs + 0 * DD, lnw + 0 * DD, lnb + 0 * DD,
                                              alphas, 0, wt + 1 * DD * DD, tbufB);
    aggemm_kernel<<<NTILES, 256, 0, stream>>>(tbufB, cnt, csrc,
                                              bs + 1 * DD, lnw + 1 * DD, lnb + 1 * DD,
                                              alphas, 1, wt + 2 * DD * DD, tbufA);
    agg_final_kernel<<<NTILES, 256, 0, stream>>>(tbufA, cnt, csrc,
                                                 bs + 2 * DD, lnw + 2 * DD, lnb + 2 * DD,
                                                 alphas, 2, out);
}

// Round 4
// 229.476 us; speedup vs baseline: 1.0218x; 1.0218x over previous
//
#include <hip/hip_runtime.h>
#include <hip/hip_bf16.h>

#define NN 50000
#define EE 600000
#define DD 128
#define LL 3
#define LN_EPS 1e-5f
#define CAP 64                      // bucket capacity; max in-degree ~30 for this graph
#define CNTS 16                     // ints per degree counter (64B line each: kills atomic line contention)
#define ALD 136                     // padded LDS row stride (shorts)
#define POOL 16                     // nodes per block tile (NN = 3125 * 16 exactly)
#define NTILES (NN / POOL)          // 3125
#define FILLB ((EE + 255) / 256)    // 2344 blocks, one edge per thread

typedef __attribute__((ext_vector_type(8))) short short8;
typedef __attribute__((ext_vector_type(4))) float floatx4;
typedef __attribute__((ext_vector_type(4))) unsigned uintx4;

__device__ inline unsigned short f2bf(float f) {
    union { float f; unsigned u; } a; a.f = f;
    unsigned r = a.u + 0x7fffu + ((a.u >> 16) & 1u);  // RNE (finite values)
    return (unsigned short)(r >> 16);
}

// ---- SRSRC buffer descriptor (T8): 32-bit voffset + HW bounds check --------
__device__ inline uintx4 make_srsrc(const void* p, unsigned bytes) {
    unsigned long long a = (unsigned long long)p;
    uintx4 r;
    r.x = (unsigned)a;
    r.y = (unsigned)(a >> 32);      // stride = 0
    r.z = bytes;                    // num_records in bytes (stride==0)
    r.w = 0x00020000u;              // raw untyped dword access
    return r;
}

__device__ inline uintx4 bload(uintx4 srsrc, unsigned voff) {
    uintx4 r;
    asm volatile("buffer_load_dwordx4 %0, %1, %2, 0 offen"
                 : "=v"(r) : "v"(voff), "s"(srsrc));
    return r;
}

#define WAITV(n) do { \
    asm volatile("s_waitcnt vmcnt(" #n ")" ::: "memory"); \
    __builtin_amdgcn_sched_barrier(0); \
} while (0)

// ------- init: zero cnt + zero-pad rows of both T buffers + W -> Wt bf16 ----
// (in-kernel, NOT hipMemsetAsync: the runtime expands that into a fillBuffer)

__global__ __launch_bounds__(256) void init_kernel(const float* __restrict__ W,
                                                   unsigned short* __restrict__ Wt,
                                                   int* __restrict__ cnt,
                                                   unsigned short* __restrict__ tbufA,
                                                   unsigned short* __restrict__ tbufB) {
    int tid = blockIdx.x * 256 + threadIdx.x;
    for (int i = tid; i < NN * CNTS / 4; i += gridDim.x * 256)
        ((int4*)cnt)[i] = make_int4(0, 0, 0, 0);
    // zero rows NN..NN+15 of both T buffers (row NN = gather pad target)
    for (int i = tid; i < 16 * DD / 2; i += gridDim.x * 256) {
        ((int*)&tbufA[(size_t)NN * DD])[i] = 0;
        ((int*)&tbufB[(size_t)NN * DD])[i] = 0;
    }
    // Wt[l][n][k] = bf16(W[l][k][n])
    for (int i = tid; i < LL * DD * DD; i += gridDim.x * 256) {
        int l = i >> 14, n = (i >> 7) & 127, k = i & 127;
        Wt[i] = f2bf(W[(l << 14) + k * DD + n]);
    }
}

// ------ fill: one edge per thread, padded counters ---------------------------

__global__ __launch_bounds__(256) void fill_kernel(
    const int* __restrict__ src, const int* __restrict__ dst,
    int* __restrict__ cnt, int* __restrict__ csrc) {
    int e = blockIdx.x * 256 + threadIdx.x;
    if (e < EE) {
        int d = dst[e];
        int s = src[e];
        int pos = atomicAdd(&cnt[d * CNTS], 1);
        csrc[(size_t)d * CAP + pos] = s;
    }
}

// ------ gemm0: Tb' = bf16( (x @ W0) * dinv )  (pre-scaled rows) ------------

__global__ __launch_bounds__(256) void gemm0_kernel(
    const float* __restrict__ A, const unsigned short* __restrict__ Wt,
    const int* __restrict__ cnt, unsigned short* __restrict__ Cb) {
    __shared__ unsigned short alds[POOL * ALD];
    __shared__ float s_dinv[POOL];
    int tid = threadIdx.x;
    int lane = tid & 63;
    int w = tid >> 6;
    int nodebase = blockIdx.x * POOL;

    if (tid < POOL)
        s_dinv[tid] = rsqrtf((float)(cnt[(nodebase + tid) * CNTS] + 1));

    {
        int row = tid >> 4;
        int kc = (tid & 15) * 8;
        const float* ap = &A[(size_t)(nodebase + row) * DD + kc];
        float4 v0 = *(const float4*)&ap[0];
        float4 v1 = *(const float4*)&ap[4];
        float fv[8] = {v0.x, v0.y, v0.z, v0.w, v1.x, v1.y, v1.z, v1.w};
        unsigned short uv[8];
        #pragma unroll
        for (int q = 0; q < 8; q++) uv[q] = f2bf(fv[q]);
        *(uint4*)&alds[row * ALD + kc] = *(uint4*)&uv[0];
    }
    __syncthreads();

    int cbase = w * 32;
    int kq = (lane >> 4) * 8;
    int mrow = lane & 15;
    floatx4 acc[2] = {{0.f,0.f,0.f,0.f},{0.f,0.f,0.f,0.f}};
    #pragma unroll
    for (int t = 0; t < 4; t++) {
        short8 a = *(const short8*)&alds[mrow * ALD + t * 32 + kq];
        #pragma unroll
        for (int j = 0; j < 2; j++) {
            short8 b = *(const short8*)&Wt[(cbase + j * 16 + (lane & 15)) * DD + t * 32 + kq];
            acc[j] = __builtin_amdgcn_mfma_f32_16x16x32_bf16(a, b, acc[j], 0, 0, 0);
        }
    }
    __syncthreads();

    {
        int r0 = (lane >> 4) * 4;
        #pragma unroll
        for (int i = 0; i < 4; i++) {
            float dvr = s_dinv[r0 + i];
            #pragma unroll
            for (int j = 0; j < 2; j++)
                alds[(r0 + i) * ALD + cbase + j * 16 + (lane & 15)] = f2bf(acc[j][i] * dvr);
        }
    }
    __syncthreads();
    {
        int srow = tid >> 4;
        int scol = (tid & 15) * 8;
        *(uint4*)&Cb[(size_t)(nodebase + srow) * DD + scol] =
            *(uint4*)&alds[srow * ALD + scol];
    }
}

// --------- agg: pipelined gather, counted vmcnt, zero-row padding -----------
// Tb rows PRE-SCALED by dinv[src]; slots k>=deg read zero row NN (adds 0).
// 16-lane group, lane owns 8 feats. Window of 8 gathers in flight, never
// drained to 0 in the main window (T4).

__device__ inline void acc_row(float* acc, uintx4 t) {
    #pragma unroll
    for (int q = 0; q < 4; q++) {
        union { unsigned x; float f; } lo, hi;
        lo.x = t[q] << 16;
        hi.x = t[q] & 0xffff0000u;
        acc[2 * q]     += lo.f;
        acc[2 * q + 1] += hi.f;
    }
}

__device__ inline void agg_node(uintx4 srsrc,
                                const int* __restrict__ cnt, const int* __restrict__ csrc,
                                const float* bv, const float* wv, const float* cv,
                                float alpha, int node, int f8, float* yv, float* dv_out) {
    int deg = cnt[node * CNTS];
    float dv = rsqrtf((float)(deg + 1));
    *dv_out = dv;
    const int* row = &csrc[(size_t)node * CAP];
    unsigned vbase = (unsigned)f8 * 2u;           // byte offset within 256B row

    // preload 16 indices (plain loads; drained before the asm window)
    int4 i0 = *(const int4*)&row[0];
    int4 i1 = *(const int4*)&row[4];
    int4 i2 = *(const int4*)&row[8];
    int4 i3 = *(const int4*)&row[12];
    int idx[16] = {i0.x, i0.y, i0.z, i0.w, i1.x, i1.y, i1.z, i1.w,
                   i2.x, i2.y, i2.z, i2.w, i3.x, i3.y, i3.z, i3.w};
    unsigned voff[16];
    #pragma unroll
    for (int k = 0; k < 16; k++) {
        int s = (k < deg) ? idx[k] : NN;          // pad -> zero row
        voff[k] = ((unsigned)s << 8) + vbase;
    }
    unsigned voffself = ((unsigned)node << 8) + vbase;

    // ---- deterministic vmcnt window: only asm VMEM below this drain ----
    WAITV(0);
    uintx4 ts = bload(srsrc, voffself);                           // 1 in flight
    uintx4 t0 = bload(srsrc, voff[0]),  t1 = bload(srsrc, voff[1]);
    uintx4 t2 = bload(srsrc, voff[2]),  t3 = bload(srsrc, voff[3]);   // 5
    uintx4 t4 = bload(srsrc, voff[4]),  t5 = bload(srsrc, voff[5]);
    uintx4 t6 = bload(srsrc, voff[6]),  t7 = bload(srsrc, voff[7]);   // 9

    float acc[8] = {};
    WAITV(8);                                     // self done
    acc_row(acc, ts);
    WAITV(4);                                     // t0..t3 done
    acc_row(acc, t0); acc_row(acc, t1); acc_row(acc, t2); acc_row(acc, t3);
    uintx4 u0 = bload(srsrc, voff[8]),  u1 = bload(srsrc, voff[9]);
    uintx4 u2 = bload(srsrc, voff[10]), u3 = bload(srsrc, voff[11]);  // t4..7 + u = 8
    WAITV(4);                                     // t4..t7 done
    acc_row(acc, t4); acc_row(acc, t5); acc_row(acc, t6); acc_row(acc, t7);
    uintx4 w0 = bload(srsrc, voff[12]), w1 = bload(srsrc, voff[13]);
    uintx4 w2 = bload(srsrc, voff[14]), w3 = bload(srsrc, voff[15]);  // u + w = 8
    WAITV(4);                                     // u0..u3 done
    acc_row(acc, u0); acc_row(acc, u1); acc_row(acc, u2); acc_row(acc, u3);
    WAITV(0);                                     // w0..w3 done
    acc_row(acc, w0); acc_row(acc, w1); acc_row(acc, w2); acc_row(acc, w3);

    // rare tail: deg > 16 (drain-style, divergent ok)
    for (int k = 16; k < deg; k += 4) {
        int4 ss = *(const int4*)&row[k];
        unsigned v0 = ((unsigned)ss.x << 8) + vbase;
        unsigned v1 = ((unsigned)((k + 1 < deg) ? ss.y : NN) << 8) + vbase;
        unsigned v2 = ((unsigned)((k + 2 < deg) ? ss.z : NN) << 8) + vbase;
        unsigned v3 = ((unsigned)((k + 3 < deg) ? ss.w : NN) << 8) + vbase;
        uintx4 a0 = bload(srsrc, v0), a1 = bload(srsrc, v1);
        uintx4 a2 = bload(srsrc, v2), a3 = bload(srsrc, v3);
        WAITV(0);
        acc_row(acc, a0); acc_row(acc, a1); acc_row(acc, a2); acc_row(acc, a3);
    }

    float a[8];
    float s1 = 0.f, s2 = 0.f;
    #pragma unroll
    for (int q = 0; q < 8; q++) {
        a[q] = fmaf(acc[q], dv, bv[q]);
        s1 += a[q]; s2 += a[q] * a[q];
    }
    #pragma unroll
    for (int off = 8; off > 0; off >>= 1) {
        s1 += __shfl_xor(s1, off, 16);
        s2 += __shfl_xor(s2, off, 16);
    }
    float mu = s1 * (1.f / DD);
    float var = s2 * (1.f / DD) - mu * mu;
    float rstd = rsqrtf(var + LN_EPS);
    #pragma unroll
    for (int q = 0; q < 8; q++) {
        float y = (a[q] - mu) * rstd * wv[q] + cv[q];
        yv[q] = (y >= 0.f) ? y : alpha * y;
    }
}

// ------- fused agg(layer l) + gemm(layer l+1): Tb' -> Tout' (pre-scaled) ----

__global__ __launch_bounds__(256) void aggemm_kernel(
    const unsigned short* __restrict__ Tb, const int* __restrict__ cnt,
    const int* __restrict__ csrc,
    const float* __restrict__ bias, const float* __restrict__ lnw,
    const float* __restrict__ lnb, const float* __restrict__ alphas, int layer,
    const unsigned short* __restrict__ Wt, unsigned short* __restrict__ Tout) {
    __shared__ unsigned short alds[POOL * ALD];
    __shared__ float s_dinv[POOL];
    int tid = threadIdx.x;
    int g = tid >> 4;
    int lane16 = tid & 15;
    int f8 = lane16 * 8;
    int nodebase = blockIdx.x * POOL;

    uintx4 srsrc = make_srsrc(Tb, (NN + 1) * DD * 2);

    float4 b0 = *(const float4*)&bias[f8];
    float4 b1 = *(const float4*)&bias[f8 + 4];
    float4 w0 = *(const float4*)&lnw[f8];
    float4 w1 = *(const float4*)&lnw[f8 + 4];
    float4 c0 = *(const float4*)&lnb[f8];
    float4 c1 = *(const float4*)&lnb[f8 + 4];
    float bv[8] = {b0.x, b0.y, b0.z, b0.w, b1.x, b1.y, b1.z, b1.w};
    float wv[8] = {w0.x, w0.y, w0.z, w0.w, w1.x, w1.y, w1.z, w1.w};
    float cv[8] = {c0.x, c0.y, c0.z, c0.w, c1.x, c1.y, c1.z, c1.w};
    float alpha = alphas[layer];

    {   // NN == 3125*16: node always in range
        int node = nodebase + g;
        float yv[8], dv;
        agg_node(srsrc, cnt, csrc, bv, wv, cv, alpha, node, f8, yv, &dv);
        if (lane16 == 0) s_dinv[g] = dv;
        unsigned short pv[8];
        #pragma unroll
        for (int q = 0; q < 8; q++) pv[q] = f2bf(yv[q]);
        *(uint4*)&alds[g * ALD + f8] = *(uint4*)&pv[0];
    }
    __syncthreads();

    // MFMA: C = Y @ W_{l+1}, rows pre-scaled by dinv in the epilogue.
    int lane = tid & 63;
    int w = tid >> 6;
    int cbase = w * 32;
    int kq = (lane >> 4) * 8;
    int mrow = lane & 15;
    floatx4 acc[2] = {{0.f,0.f,0.f,0.f},{0.f,0.f,0.f,0.f}};
    #pragma unroll
    for (int t = 0; t < 4; t++) {
        short8 a = *(const short8*)&alds[mrow * ALD + t * 32 + kq];
        #pragma unroll
        for (int j = 0; j < 2; j++) {
            short8 b = *(const short8*)&Wt[(cbase + j * 16 + (lane & 15)) * DD + t * 32 + kq];
            acc[j] = __builtin_amdgcn_mfma_f32_16x16x32_bf16(a, b, acc[j], 0, 0, 0);
        }
    }
    __syncthreads();   // alds reads done before transpose overwrites

    {
        int r0 = (lane >> 4) * 4;
        #pragma unroll
        for (int i = 0; i < 4; i++) {
            float dvr = s_dinv[r0 + i];
            #pragma unroll
            for (int j = 0; j < 2; j++)
                alds[(r0 + i) * ALD + cbase + j * 16 + (lane & 15)] = f2bf(acc[j][i] * dvr);
        }
    }
    __syncthreads();
    {
        int srow = tid >> 4;
        int scol = (tid & 15) * 8;
        *(uint4*)&Tout[(size_t)(nodebase + srow) * DD + scol] =
            *(uint4*)&alds[srow * ALD + scol];
    }
}

// ---------------- final agg: layer 2, f32 output ----------------

__global__ __launch_bounds__(256) void agg_final_kernel(
    const unsigned short* __restrict__ Tb, const int* __restrict__ cnt,
    const int* __restrict__ csrc,
    const float* __restrict__ bias, const float* __restrict__ lnw,
    const float* __restrict__ lnb, const float* __restrict__ alphas, int layer,
    float* __restrict__ out) {
    int g = threadIdx.x >> 4;
    int lane16 = threadIdx.x & 15;
    int f8 = lane16 * 8;
    int node = blockIdx.x * POOL + g;

    uintx4 srsrc = make_srsrc(Tb, (NN + 1) * DD * 2);

    float4 b0 = *(const float4*)&bias[f8];
    float4 b1 = *(const float4*)&bias[f8 + 4];
    float4 w0 = *(const float4*)&lnw[f8];
    float4 w1 = *(const float4*)&lnw[f8 + 4];
    float4 c0 = *(const float4*)&lnb[f8];
    float4 c1 = *(const float4*)&lnb[f8 + 4];
    float bv[8] = {b0.x, b0.y, b0.z, b0.w, b1.x, b1.y, b1.z, b1.w};
    float wv[8] = {w0.x, w0.y, w0.z, w0.w, w1.x, w1.y, w1.z, w1.w};
    float cv[8] = {c0.x, c0.y, c0.z, c0.w, c1.x, c1.y, c1.z, c1.w};

    float yv[8], dv;
    agg_node(srsrc, cnt, csrc, bv, wv, cv, alphas[layer], node, f8, yv, &dv);

    float* op = &out[(size_t)node * DD + f8];
    *(float4*)&op[0] = make_float4(yv[0], yv[1], yv[2], yv[3]);
    *(float4*)&op[4] = make_float4(yv[4], yv[5], yv[6], yv[7]);
}

// ---------------- launch ----------------

extern "C" void kernel_launch(void* const* d_in, const int* in_sizes, int n_in,
                              void* d_out, int out_size, void* d_ws, size_t ws_size,
                              hipStream_t stream) {
    const float* x    = (const float*)d_in[0];
    const int*   ei   = (const int*)d_in[1];
    const float* Ws   = (const float*)d_in[2];
    const float* bs   = (const float*)d_in[3];
    const float* lnw  = (const float*)d_in[4];
    const float* lnb  = (const float*)d_in[5];
    const float* alphas = (const float*)d_in[6];
    float* out = (float*)d_out;

    const int* src = ei;
    const int* dst = ei + EE;

    char* ws = (char*)d_ws;
    size_t off = 0;
    auto alloc = [&](size_t bytes) -> void* {
        void* p = ws + off;
        off = (off + bytes + 255) & ~(size_t)255;
        return p;
    };
    int* cnt  = (int*)alloc((size_t)NN * CNTS * sizeof(int));
    int* csrc = (int*)alloc((size_t)NN * CAP * sizeof(int));
    unsigned short* wt    = (unsigned short*)alloc((size_t)LL * DD * DD * sizeof(unsigned short));
    unsigned short* tbufA = (unsigned short*)alloc((size_t)(NN + 16) * DD * sizeof(unsigned short));
    unsigned short* tbufB = (unsigned short*)alloc((size_t)(NN + 16) * DD * sizeof(unsigned short));

    init_kernel<<<512, 256, 0, stream>>>(Ws, wt, cnt, tbufA, tbufB);
    fill_kernel<<<FILLB, 256, 0, stream>>>(src, dst, cnt, csrc);
    gemm0_kernel<<<NTILES, 256, 0, stream>>>(x, wt, cnt, tbufA);

    aggemm_kernel<<<NTILES, 256, 0, stream>>>(tbufA, cnt, csrc,
                                              bs + 0 * DD, lnw + 0 * DD, lnb + 0 * DD,
                                              alphas, 0, wt + 1 * DD * DD, tbufB);
    aggemm_kernel<<<NTILES, 256, 0, stream>>>(tbufB, cnt, csrc,
                                              bs + 1 * DD, lnw + 1 * DD, lnb + 1 * DD,
                                              alphas, 1, wt + 2 * DD * DD, tbufA);
    agg_final_kernel<<<NTILES, 256, 0, stream>>>(tbufA, cnt, csrc,
                                                 bs + 2 * DD, lnw + 2 * DD, lnb + 2 * DD,
                                                 alphas, 2, out);
}